// Round 2
// baseline (331.818 us; speedup 1.0000x reference)
//
#include <hip/hip_runtime.h>
#include <math.h>

namespace {
constexpr int Bn = 4, Rn = 16384, Sn = 128;
constexpr int NRAY = Bn * Rn;          // 65536 rays
constexpr int SI   = Sn - 1;           // 127 intervals
// Output layout: tuple concatenated flat in return order
constexpr size_t OFF_RGB   = 0;                                  // [B,R,3]
constexpr size_t OFF_DEPTH = OFF_RGB   + (size_t)NRAY * 3;       // [B,R,1]
constexpr size_t OFF_W     = OFF_DEPTH + (size_t)NRAY;           // [B,R,SI,1]
constexpr size_t OFF_WALL  = OFF_W     + (size_t)NRAY * SI;      // [B,R,SI,1]
constexpr size_t OFF_ALPHA = OFF_WALL  + (size_t)NRAY * SI;      // [B,R,SI,1]
constexpr size_t OFF_DMID  = OFF_ALPHA + (size_t)NRAY * SI;      // [B,R,SI,1]
constexpr float  EPSF      = 1e-10f;
}

// ---- DPP helpers (pure-VALU cross-lane; no LDS/bpermute) ----
// ctrl encodings (gfx9/CDNA): row_shr:N = 0x110|N, wave_shl:1 = 0x130,
// wave_shr:1 = 0x138, row_bcast:15 = 0x142, row_bcast:31 = 0x143.
// ROW_MASK: lanes in masked-out rows return `oldv` (write suppressed).
template<int CTRL, int ROW_MASK, bool BC>
__device__ __forceinline__ float dpp_mov(float oldv, float src) {
    return __int_as_float(__builtin_amdgcn_update_dpp(
        __float_as_int(oldv), __float_as_int(src), CTRL, ROW_MASK, 0xF, BC));
}

// 64-lane inclusive prefix PRODUCT.
// GPUOpen scan sequence; the row masks on the bcast steps are REQUIRED:
// bcast15 must only update rows 1,3 (mask 0xa) and bcast31 rows 2,3 (0xc),
// otherwise row 2 receives row 1's total twice. Masked / invalid-source
// lanes return oldv = 1.0 (multiplicative identity).
__device__ __forceinline__ float wave_prefix_prod(float s) {
    s *= dpp_mov<0x111, 0xF, false>(1.0f, s);   // row_shr:1
    s *= dpp_mov<0x112, 0xF, false>(1.0f, s);   // row_shr:2
    s *= dpp_mov<0x114, 0xF, false>(1.0f, s);   // row_shr:4
    s *= dpp_mov<0x118, 0xF, false>(1.0f, s);   // row_shr:8
    s *= dpp_mov<0x142, 0xa, false>(1.0f, s);   // row_bcast:15 -> rows 1,3
    s *= dpp_mov<0x143, 0xc, false>(1.0f, s);   // row_bcast:31 -> rows 2,3
    return s;
}

// 64-lane sum; lane 63 holds the total afterwards. bound_ctrl=true -> invalid
// source lanes contribute 0; bcast row masks as above (masked lanes add oldv=0).
__device__ __forceinline__ float wave_sum_last(float x) {
    x += dpp_mov<0x111, 0xF, true>(0.0f, x);
    x += dpp_mov<0x112, 0xF, true>(0.0f, x);
    x += dpp_mov<0x114, 0xF, true>(0.0f, x);
    x += dpp_mov<0x118, 0xF, true>(0.0f, x);
    x += dpp_mov<0x142, 0xa, true>(0.0f, x);
    x += dpp_mov<0x143, 0xc, true>(0.0f, x);
    return x;
}

// One wave (64 lanes) per ray; lane i owns intervals 2i and 2i+1.
__global__ __launch_bounds__(256) void raymarch_kernel(
    const float* __restrict__ colors,
    const float* __restrict__ dlog,
    const float* __restrict__ depths,
    float* __restrict__ out)
{
    const int gtid = blockIdx.x * 256 + threadIdx.x;
    const int ray  = gtid >> 6;
    const int lane = threadIdx.x & 63;

    // Per-ray data is contiguous: depths/density 128 floats, colors 384 floats.
    const float2* dp = reinterpret_cast<const float2*>(depths) + (size_t)ray * (Sn / 2);
    const float2* gp = reinterpret_cast<const float2*>(dlog)   + (size_t)ray * (Sn / 2);
    const float2* cp = reinterpret_cast<const float2*>(colors) + (size_t)ray * (Sn * 3 / 2);

    float2 d  = dp[lane];          // samples 2i, 2i+1 depths
    float2 g  = gp[lane];          // density logits
    float2 c0 = cp[lane * 3 + 0];  // colors: floats 6i..6i+5 = samples 2i, 2i+1
    float2 c1 = cp[lane * 3 + 1];
    float2 c2 = cp[lane * 3 + 2];

    // sample 2i+2 lives in lane i+1's first slots: wave_shl:1 (lane i <- lane i+1).
    // Lane 63's result is its own old value, unused because valid1 is false.
    float d2  = dpp_mov<0x130, 0xF, false>(d.x,  d.x);
    float g2  = dpp_mov<0x130, 0xF, false>(g.x,  g.x);
    float cnx = dpp_mov<0x130, 0xF, false>(c0.x, c0.x);
    float cny = dpp_mov<0x130, 0xF, false>(c0.y, c0.y);
    float cnz = dpp_mov<0x130, 0xF, false>(c1.x, c1.x);

    const bool valid1 = (lane < 63);   // interval 2*63+1 = 127 does not exist

    // interval j0 = 2i : samples (2i, 2i+1)
    float delta0 = d.y - d.x;
    float dm0    = 0.5f * (d.x + d.y);
    float x0     = 0.5f * (g.x + g.y) - 1.0f;
    float cm0x   = 0.5f * (c0.x + c1.y);
    float cm0y   = 0.5f * (c0.y + c2.x);
    float cm0z   = 0.5f * (c1.x + c2.y);

    // interval j1 = 2i+1 : samples (2i+1, 2i+2) — safe values when invalid
    float delta1 = valid1 ? (d2 - d.y)            : 0.0f;
    float dm1    = valid1 ? 0.5f * (d.y + d2)     : 0.0f;
    float x1     = valid1 ? (0.5f * (g.y + g2) - 1.0f) : 0.0f;
    float cm1x   = valid1 ? 0.5f * (c1.y + cnx)   : 0.0f;
    float cm1y   = valid1 ? 0.5f * (c2.x + cny)   : 0.0f;
    float cm1z   = valid1 ? 0.5f * (c2.y + cnz)   : 0.0f;

    // alpha = 1 - exp(-softplus(x)*delta) = 1 - 2^(-delta * log2(1+e^x))
    // Hardware TRANS ops only: v_exp (via __expf), v_log (__log2f), v_exp (exp2f).
    // Limits: x -> -inf: l=0, alpha=0.  x -> +inf: l=inf (clamped) -> alpha=1.
    float l0 = __log2f(1.0f + __expf(x0));
    float l1 = __log2f(1.0f + __expf(x1));
    l0 = fminf(l0, 1e30f);                 // guard inf*0 -> NaN when delta==0
    l1 = fminf(l1, 1e30f);
    float E0 = exp2f(-delta0 * l0);        // = 1 - alpha0
    float E1 = exp2f(-delta1 * l1);
    float alpha0 = 1.0f - E0;
    float alpha1 = 1.0f - E1;              // == 0 for lane 63 (delta1=0)
    float t0 = E0 + EPSF;
    float t1 = valid1 ? (E1 + EPSF) : 1.0f;

    // wave-wide inclusive prefix PRODUCT of p = t0*t1 (cumprod replacement),
    // all DPP (no LDS pipe, no bpermute address math).
    float s  = wave_prefix_prod(t0 * t1);
    float T0 = dpp_mov<0x138, 0xF, false>(1.0f, s);   // wave_shr:1, exclusive; lane0 -> 1.0
    float T1 = T0 * t0;

    float w0 = (alpha0 + EPSF) * T0;
    float w1 = valid1 ? (alpha1 + EPSF) * T1 : 0.0f;

    // per-interval outputs: contiguous 127-float span per ray per array.
    // Streaming, never re-read -> non-temporal to keep L2/L3 for the inputs.
    size_t base = (size_t)ray * SI + 2 * lane;
    __builtin_nontemporal_store(w0,     out + OFF_W     + base);
    __builtin_nontemporal_store(w0,     out + OFF_WALL  + base);
    __builtin_nontemporal_store(alpha0, out + OFF_ALPHA + base);
    __builtin_nontemporal_store(dm0,    out + OFF_DMID  + base);
    if (valid1) {
        __builtin_nontemporal_store(w1,     out + OFF_W     + base + 1);
        __builtin_nontemporal_store(w1,     out + OFF_WALL  + base + 1);
        __builtin_nontemporal_store(alpha1, out + OFF_ALPHA + base + 1);
        __builtin_nontemporal_store(dm1,    out + OFF_DMID  + base + 1);
    }

    // composite reductions over the wave — DPP scan-sums, totals land on lane 63
    float wsum = wave_sum_last(w0 + w1);
    float rx   = wave_sum_last(w0 * cm0x + w1 * cm1x);
    float ry   = wave_sum_last(w0 * cm0y + w1 * cm1y);
    float rz   = wave_sum_last(w0 * cm0z + w1 * cm1z);
    float dsum = wave_sum_last(w0 * dm0  + w1 * dm1);

    if (lane == 63) {
        float cd = dsum / (EPSF + wsum);
        if (isnan(cd)) cd = 100.0f;                 // nan_to_num(nan=MAX_DEPTH)
        cd = fminf(fmaxf(cd, 0.1f), 100.0f);        // clip; also maps ±inf
        out[OFF_RGB + (size_t)ray * 3 + 0] = rx * 2.0f - 1.0f;
        out[OFF_RGB + (size_t)ray * 3 + 1] = ry * 2.0f - 1.0f;
        out[OFF_RGB + (size_t)ray * 3 + 2] = rz * 2.0f - 1.0f;
        out[OFF_DEPTH + ray] = cd;
    }
}

extern "C" void kernel_launch(void* const* d_in, const int* in_sizes, int n_in,
                              void* d_out, int out_size, void* d_ws, size_t ws_size,
                              hipStream_t stream) {
    const float* colors = (const float*)d_in[0];
    const float* dlog   = (const float*)d_in[1];
    const float* depths = (const float*)d_in[2];
    float* out = (float*)d_out;

    dim3 grid(NRAY / 4);   // 4 waves per 256-thread block, one ray per wave
    dim3 block(256);
    hipLaunchKernelGGL(raymarch_kernel, grid, block, 0, stream, colors, dlog, depths, out);
}

// Round 3
// 261.583 us; speedup vs baseline: 1.2685x; 1.2685x over previous
//
#include <hip/hip_runtime.h>
#include <math.h>

namespace {
constexpr int Bn = 4, Rn = 16384, Sn = 128;
constexpr int NRAY = Bn * Rn;          // 65536 rays
constexpr int SI   = Sn - 1;           // 127 intervals
// Output layout: tuple concatenated flat in return order
constexpr size_t OFF_RGB   = 0;                                  // [B,R,3]
constexpr size_t OFF_DEPTH = OFF_RGB   + (size_t)NRAY * 3;       // [B,R,1]
constexpr size_t OFF_W     = OFF_DEPTH + (size_t)NRAY;           // [B,R,SI,1]
constexpr size_t OFF_WALL  = OFF_W     + (size_t)NRAY * SI;      // [B,R,SI,1]
constexpr size_t OFF_ALPHA = OFF_WALL  + (size_t)NRAY * SI;      // [B,R,SI,1]
constexpr size_t OFF_DMID  = OFF_ALPHA + (size_t)NRAY * SI;      // [B,R,SI,1]
constexpr float  EPSF      = 1e-10f;
}

// ---- DPP helpers (pure-VALU cross-lane; no LDS/bpermute) ----
// ctrl encodings (gfx9/CDNA): row_shr:N = 0x110|N, wave_shl:1 = 0x130,
// wave_shr:1 = 0x138, row_bcast:15 = 0x142, row_bcast:31 = 0x143.
// ROW_MASK: lanes in masked-out rows return `oldv` (write suppressed).
template<int CTRL, int ROW_MASK, bool BC>
__device__ __forceinline__ float dpp_mov(float oldv, float src) {
    return __int_as_float(__builtin_amdgcn_update_dpp(
        __float_as_int(oldv), __float_as_int(src), CTRL, ROW_MASK, 0xF, BC));
}

// 64-lane inclusive prefix PRODUCT.
// GPUOpen scan sequence; the row masks on the bcast steps are REQUIRED:
// bcast15 must only update rows 1,3 (mask 0xa) and bcast31 rows 2,3 (0xc),
// otherwise row 2 receives row 1's total twice. Masked / invalid-source
// lanes return oldv = 1.0 (multiplicative identity).
__device__ __forceinline__ float wave_prefix_prod(float s) {
    s *= dpp_mov<0x111, 0xF, false>(1.0f, s);   // row_shr:1
    s *= dpp_mov<0x112, 0xF, false>(1.0f, s);   // row_shr:2
    s *= dpp_mov<0x114, 0xF, false>(1.0f, s);   // row_shr:4
    s *= dpp_mov<0x118, 0xF, false>(1.0f, s);   // row_shr:8
    s *= dpp_mov<0x142, 0xa, false>(1.0f, s);   // row_bcast:15 -> rows 1,3
    s *= dpp_mov<0x143, 0xc, false>(1.0f, s);   // row_bcast:31 -> rows 2,3
    return s;
}

// 64-lane sum; lane 63 holds the total afterwards. bound_ctrl=true -> invalid
// source lanes contribute 0; bcast row masks as above (masked lanes add oldv=0).
__device__ __forceinline__ float wave_sum_last(float x) {
    x += dpp_mov<0x111, 0xF, true>(0.0f, x);
    x += dpp_mov<0x112, 0xF, true>(0.0f, x);
    x += dpp_mov<0x114, 0xF, true>(0.0f, x);
    x += dpp_mov<0x118, 0xF, true>(0.0f, x);
    x += dpp_mov<0x142, 0xa, true>(0.0f, x);
    x += dpp_mov<0x143, 0xc, true>(0.0f, x);
    return x;
}

// One wave (64 lanes) per ray; lane i owns intervals 2i and 2i+1.
__global__ __launch_bounds__(256) void raymarch_kernel(
    const float* __restrict__ colors,
    const float* __restrict__ dlog,
    const float* __restrict__ depths,
    float* __restrict__ out)
{
    const int gtid = blockIdx.x * 256 + threadIdx.x;
    const int ray  = gtid >> 6;
    const int lane = threadIdx.x & 63;

    // Per-ray data is contiguous: depths/density 128 floats, colors 384 floats.
    const float2* dp = reinterpret_cast<const float2*>(depths) + (size_t)ray * (Sn / 2);
    const float2* gp = reinterpret_cast<const float2*>(dlog)   + (size_t)ray * (Sn / 2);
    const float2* cp = reinterpret_cast<const float2*>(colors) + (size_t)ray * (Sn * 3 / 2);

    float2 d  = dp[lane];          // samples 2i, 2i+1 depths
    float2 g  = gp[lane];          // density logits
    float2 c0 = cp[lane * 3 + 0];  // colors: floats 6i..6i+5 = samples 2i, 2i+1
    float2 c1 = cp[lane * 3 + 1];
    float2 c2 = cp[lane * 3 + 2];

    // sample 2i+2 lives in lane i+1's first slots: wave_shl:1 (lane i <- lane i+1).
    // Lane 63's result is its own old value, unused because valid1 is false.
    float d2  = dpp_mov<0x130, 0xF, false>(d.x,  d.x);
    float g2  = dpp_mov<0x130, 0xF, false>(g.x,  g.x);
    float cnx = dpp_mov<0x130, 0xF, false>(c0.x, c0.x);
    float cny = dpp_mov<0x130, 0xF, false>(c0.y, c0.y);
    float cnz = dpp_mov<0x130, 0xF, false>(c1.x, c1.x);

    const bool valid1 = (lane < 63);   // interval 2*63+1 = 127 does not exist

    // interval j0 = 2i : samples (2i, 2i+1)
    float delta0 = d.y - d.x;
    float dm0    = 0.5f * (d.x + d.y);
    float x0     = 0.5f * (g.x + g.y) - 1.0f;
    float cm0x   = 0.5f * (c0.x + c1.y);
    float cm0y   = 0.5f * (c0.y + c2.x);
    float cm0z   = 0.5f * (c1.x + c2.y);

    // interval j1 = 2i+1 : samples (2i+1, 2i+2) — safe values when invalid
    float delta1 = valid1 ? (d2 - d.y)            : 0.0f;
    float dm1    = valid1 ? 0.5f * (d.y + d2)     : 0.0f;
    float x1     = valid1 ? (0.5f * (g.y + g2) - 1.0f) : 0.0f;
    float cm1x   = valid1 ? 0.5f * (c1.y + cnx)   : 0.0f;
    float cm1y   = valid1 ? 0.5f * (c2.x + cny)   : 0.0f;
    float cm1z   = valid1 ? 0.5f * (c2.y + cnz)   : 0.0f;

    // alpha = 1 - exp(-softplus(x)*delta) = 1 - 2^(-delta * log2(1+e^x))
    // Hardware TRANS ops only: v_exp (via __expf), v_log (__log2f), v_exp (exp2f).
    // Limits: x -> -inf: l=0, alpha=0.  x -> +inf: l=inf (clamped) -> alpha=1.
    float l0 = __log2f(1.0f + __expf(x0));
    float l1 = __log2f(1.0f + __expf(x1));
    l0 = fminf(l0, 1e30f);                 // guard inf*0 -> NaN when delta==0
    l1 = fminf(l1, 1e30f);
    float E0 = exp2f(-delta0 * l0);        // = 1 - alpha0
    float E1 = exp2f(-delta1 * l1);
    float alpha0 = 1.0f - E0;
    float alpha1 = 1.0f - E1;              // == 0 for lane 63 (delta1=0)
    float t0 = E0 + EPSF;
    float t1 = valid1 ? (E1 + EPSF) : 1.0f;

    // wave-wide inclusive prefix PRODUCT of p = t0*t1 (cumprod replacement),
    // all DPP (no LDS pipe, no bpermute address math).
    float s  = wave_prefix_prod(t0 * t1);
    float T0 = dpp_mov<0x138, 0xF, false>(1.0f, s);   // wave_shr:1, exclusive; lane0 -> 1.0
    float T1 = T0 * t0;

    float w0 = (alpha0 + EPSF) * T0;
    float w1 = valid1 ? (alpha1 + EPSF) * T1 : 0.0f;

    // per-interval outputs: contiguous 127-float span per ray per array.
    // Plain cached stores: spans of adjacent rays share 64B lines, and L2
    // write-back merges the partial writes into full-line HBM writes.
    // (nt stores evicted lines early -> 2x WRITE_SIZE. Measured round 2.)
    size_t base = (size_t)ray * SI + 2 * lane;
    out[OFF_W     + base] = w0;
    out[OFF_WALL  + base] = w0;
    out[OFF_ALPHA + base] = alpha0;
    out[OFF_DMID  + base] = dm0;
    if (valid1) {
        out[OFF_W     + base + 1] = w1;
        out[OFF_WALL  + base + 1] = w1;
        out[OFF_ALPHA + base + 1] = alpha1;
        out[OFF_DMID  + base + 1] = dm1;
    }

    // composite reductions over the wave — DPP scan-sums, totals land on lane 63
    float wsum = wave_sum_last(w0 + w1);
    float rx   = wave_sum_last(w0 * cm0x + w1 * cm1x);
    float ry   = wave_sum_last(w0 * cm0y + w1 * cm1y);
    float rz   = wave_sum_last(w0 * cm0z + w1 * cm1z);
    float dsum = wave_sum_last(w0 * dm0  + w1 * dm1);

    if (lane == 63) {
        float cd = dsum / (EPSF + wsum);
        if (isnan(cd)) cd = 100.0f;                 // nan_to_num(nan=MAX_DEPTH)
        cd = fminf(fmaxf(cd, 0.1f), 100.0f);        // clip; also maps ±inf
        out[OFF_RGB + (size_t)ray * 3 + 0] = rx * 2.0f - 1.0f;
        out[OFF_RGB + (size_t)ray * 3 + 1] = ry * 2.0f - 1.0f;
        out[OFF_RGB + (size_t)ray * 3 + 2] = rz * 2.0f - 1.0f;
        out[OFF_DEPTH + ray] = cd;
    }
}

extern "C" void kernel_launch(void* const* d_in, const int* in_sizes, int n_in,
                              void* d_out, int out_size, void* d_ws, size_t ws_size,
                              hipStream_t stream) {
    const float* colors = (const float*)d_in[0];
    const float* dlog   = (const float*)d_in[1];
    const float* depths = (const float*)d_in[2];
    float* out = (float*)d_out;

    dim3 grid(NRAY / 4);   // 4 waves per 256-thread block, one ray per wave
    dim3 block(256);
    hipLaunchKernelGGL(raymarch_kernel, grid, block, 0, stream, colors, dlog, depths, out);
}